// Round 5
// baseline (735.668 us; speedup 1.0000x reference)
//
#include <hip/hip_runtime.h>
#include <cstdint>
#include <cstddef>

#define S_  1024
#define B_  4
#define T_  2048
#define H_  16

typedef short     short8 __attribute__((ext_vector_type(8)));
typedef float     f32x4  __attribute__((ext_vector_type(4)));
typedef unsigned short u16x8 __attribute__((ext_vector_type(8)));

__device__ __forceinline__ unsigned short f2b(float f){
  uint32_t x = __builtin_bit_cast(uint32_t, f);
  x = (x + 0x7fffu + ((x >> 16) & 1u)) >> 16;   // RNE
  return (unsigned short)x;
}
__device__ __forceinline__ float b2f(unsigned short u){
  return __builtin_bit_cast(float, ((uint32_t)u) << 16);
}

// ---------------------------------------------------------------------------
// fp32 -> bf16 convert, with 2-source concat (for x_mem = [memory; input]).
// ---------------------------------------------------------------------------
__global__ __launch_bounds__(256) void cvt_cat(
    const float* __restrict__ a, const float* __restrict__ bsrc,
    int splitElems, int total, unsigned short* __restrict__ out)
{
  int i = (blockIdx.x * 256 + threadIdx.x) * 4;
  if (i >= total) return;
  const float* src = (i < splitElems) ? (a + i) : (bsrc + (i - splitElems));
  float4 x = *(const float4*)src;
  ushort4 o;
  o.x = f2b(x.x); o.y = f2b(x.y); o.z = f2b(x.z); o.w = f2b(x.w);
  *(ushort4*)(out + i) = o;
}

// ---------------------------------------------------------------------------
// Transpose-convert: in fp32 [R][C] -> out bf16 [C][R].
// ---------------------------------------------------------------------------
__global__ __launch_bounds__(256) void wtrans(
    const float* __restrict__ in, unsigned short* __restrict__ out, int R, int C)
{
  __shared__ float tile[32][33];
  const int R0 = blockIdx.y * 32, C0 = blockIdx.x * 32;
  const int t = threadIdx.x;
  const int r = t >> 3, c4 = (t & 7) * 4;
  float4 x = *(const float4*)(in + (size_t)(R0 + r) * C + C0 + c4);
  tile[r][c4+0] = x.x; tile[r][c4+1] = x.y; tile[r][c4+2] = x.z; tile[r][c4+3] = x.w;
  __syncthreads();
  ushort4 o;
  o.x = f2b(tile[c4+0][r]); o.y = f2b(tile[c4+1][r]);
  o.z = f2b(tile[c4+2][r]); o.w = f2b(tile[c4+3][r]);
  *(ushort4*)(out + (size_t)(C0 + r) * R + R0 + c4) = o;
}

// ---------------------------------------------------------------------------
// Transpose V-half of kv into VTg[bh*64 + d][T] (bf16) for PV B-operand.
// ---------------------------------------------------------------------------
__global__ __launch_bounds__(256) void vtrans(
    const unsigned short* __restrict__ kvb, unsigned short* __restrict__ vtg)
{
  __shared__ __align__(16) unsigned short tile[64][72];
  const int t = threadIdx.x;
  const int bh = blockIdx.y;           // b*16+h
  const int b = bh >> 4, h = bh & 15;
  const int t0 = blockIdx.x * 64;
  #pragma unroll
  for (int l = 0; l < 2; ++l){
    int idx = t + l * 256;
    int row = idx >> 3, seg = (idx & 7) * 8;
    u16x8 x = *(const u16x8*)(kvb + ((size_t)(t0 + row) * 4 + b) * 2048 + 1024 + h * 64 + seg);
    *(u16x8*)&tile[row][seg] = x;
  }
  __syncthreads();
  #pragma unroll
  for (int l = 0; l < 2; ++l){
    int idx = t + l * 256;
    int d = idx >> 3, nseg = (idx & 7) * 8;
    u16x8 o;
    #pragma unroll
    for (int j = 0; j < 8; ++j) o[j] = tile[nseg + j][d];
    *(u16x8*)(vtg + ((size_t)bh * 64 + d) * 2048 + t0 + nseg) = o;
  }
}

// ---------------------------------------------------------------------------
// bf16 MFMA GEMM: C[M][N] = A[M][K] @ BT[N][K]^T. 128x128 block tile, 4 waves
// each 64x64 (4x4 tiles of 16x16x32). Optional fp32 residual, fp32/bf16 out.
// ---------------------------------------------------------------------------
__global__ __launch_bounds__(256) void gemm_bf16(
    const unsigned short* __restrict__ A, const unsigned short* __restrict__ BT,
    int M, int N, int K,
    const float* __restrict__ resid, float* __restrict__ outF,
    unsigned short* __restrict__ outB)
{
  __shared__ __align__(16) unsigned short As[128 * 72];
  __shared__ __align__(16) unsigned short Bs[128 * 72];
  const int t = threadIdx.x;
  const int M0 = blockIdx.y * 128, N0 = blockIdx.x * 128;
  const int w = t >> 6, lane = t & 63, quad = lane >> 4, l16 = lane & 15;
  const int wm = (w >> 1) * 64, wn = (w & 1) * 64;
  const int arow = t >> 1, aseg = (t & 1) * 32;

  f32x4 acc[4][4] = {};

  for (int k0 = 0; k0 < K; k0 += 64){
    __syncthreads();
    const unsigned short* ag = A  + (size_t)(M0 + arow) * K + k0 + aseg;
    const unsigned short* bg = BT + (size_t)(N0 + arow) * K + k0 + aseg;
    #pragma unroll
    for (int j = 0; j < 4; ++j){
      *(u16x8*)&As[arow * 72 + aseg + j * 8] = *(const u16x8*)(ag + j * 8);
      *(u16x8*)&Bs[arow * 72 + aseg + j * 8] = *(const u16x8*)(bg + j * 8);
    }
    __syncthreads();
    #pragma unroll
    for (int ks = 0; ks < 2; ++ks){
      short8 af[4], bf[4];
      #pragma unroll
      for (int rt = 0; rt < 4; ++rt)
        af[rt] = *(short8*)&As[(wm + rt * 16 + l16) * 72 + ks * 32 + quad * 8];
      #pragma unroll
      for (int ct = 0; ct < 4; ++ct)
        bf[ct] = *(short8*)&Bs[(wn + ct * 16 + l16) * 72 + ks * 32 + quad * 8];
      #pragma unroll
      for (int rt = 0; rt < 4; ++rt)
        #pragma unroll
        for (int ct = 0; ct < 4; ++ct)
          acc[rt][ct] = __builtin_amdgcn_mfma_f32_16x16x32_bf16(af[rt], bf[ct], acc[rt][ct], 0, 0, 0);
    }
  }

  #pragma unroll
  for (int rt = 0; rt < 4; ++rt){
    #pragma unroll
    for (int r = 0; r < 4; ++r){
      int row = M0 + wm + rt * 16 + quad * 4 + r;
      #pragma unroll
      for (int ct = 0; ct < 4; ++ct){
        int col = N0 + wn + ct * 16 + l16;
        float val = acc[rt][ct][r];
        if (resid) val += resid[(size_t)row * N + col];
        if (outF) outF[(size_t)row * N + col] = val;
        if (outB) outB[(size_t)row * N + col] = f2b(val);
      }
    }
  }
}

// ---------------------------------------------------------------------------
// Zero-barrier MFMA flash attention with fused Transformer-XL relative shift.
// Rel-shift: delta=j-i: <=1024 -> praw[i][delta+1023]; ==1025 -> 0;
//            >=1026 -> praw[i+1][delta-1026].
// A-operands (q+u / q+v rows) live in registers; B-operands (K, V^T,
// p-window rows) are read per-lane directly from global in MFMA B-frag
// layout. Pos scores scatter writer-side into widened ScW[m][m+c]
// (reader at col n+63); Sc and P tiles are own-wave LDS only -> no
// __syncthreads in the whole kernel. Fixed-max softmax exp(s-16).
// ---------------------------------------------------------------------------
__global__ __launch_bounds__(256) void attn_mfma(
    const unsigned short* __restrict__ qb,   // (4096,1024) bf16
    const unsigned short* __restrict__ kvb,  // (8192,2048) bf16 [k|v]
    const unsigned short* __restrict__ pbm,  // (2048,1024) bf16
    const unsigned short* __restrict__ vtg,  // (64*64, 2048) bf16 V^T per (b,h)
    const float* __restrict__ ub, const float* __restrict__ vb,
    unsigned short* __restrict__ awvb)       // (4096,1024) bf16
{
  __shared__ unsigned short ScW[64 * 195];   // ScW[m][col], row stride 194, col=m+c
  __shared__ __align__(16) unsigned short Pb[64 * 72];

  const int t = threadIdx.x;
  const int i0 = blockIdx.x * 64;
  const int bh = blockIdx.y;
  const int b = bh >> 4, h = bh & 15;
  const int w = t >> 6, lane = t & 63, quad = lane >> 4, l16 = lane & 15;
  const int colbase = h * 64 + quad * 8;

  // ---- register A-fragments: qu[ks], qv[cs][ks] (wave rows 16w+l16(+cs)) ----
  short8 qu[2], qv[2][2];
  #pragma unroll
  for (int cs = 0; cs < 2; ++cs){
    int gr = i0 + 16 * w + l16 + cs;            // may reach 1024 -> OOB-safe (ws)
    #pragma unroll
    for (int ks = 0; ks < 2; ++ks){
      u16x8 q8 = *(const u16x8*)(qb + ((size_t)gr * 4 + b) * 1024 + colbase + ks * 32);
      #pragma unroll
      for (int j = 0; j < 8; ++j){
        float f = b2f(q8[j]);
        float vv = vb[colbase + ks * 32 + j];
        qv[cs][ks][j] = (short)f2b(f + vv);
        if (cs == 0){
          float uu = ub[colbase + ks * 32 + j];
          qu[ks][j] = (short)f2b(f + uu);
        }
      }
    }
  }

  f32x4 oacc[4] = {};                         // [d-tile], rows = quad*4+r
  float lsum[4] = {0.f, 0.f, 0.f, 0.f};

  // pos MFMA pass; B-frag rows read straight from global; writer-side shift
  auto posPass = [&](int cs, int rowbase, int lo, int hi, bool maskedWrite){
    f32x4 racc[8] = {};
    #pragma unroll
    for (int ks = 0; ks < 2; ++ks){
      #pragma unroll
      for (int ct = 0; ct < 8; ++ct){
        int pr = rowbase + ct * 16 + l16;
        short8 bf = *(const short8*)(pbm + (ptrdiff_t)pr * 1024 + colbase + ks * 32);
        racc[ct] = __builtin_amdgcn_mfma_f32_16x16x32_bf16(qv[cs][ks], bf, racc[ct], 0, 0, 0);
      }
    }
    #pragma unroll
    for (int ct = 0; ct < 8; ++ct){
      int c = ct * 16 + l16;
      bool valid = (c >= lo) && (c <= hi);
      #pragma unroll
      for (int r = 0; r < 4; ++r){
        int gm = 16 * w + quad * 4 + r;
        int addr = gm * 195 + c;               // = gm*194 + (gm + c)
        if (maskedWrite){
          if (valid) ScW[addr] = f2b(racc[ct][r]);
        } else {
          ScW[addr] = f2b(valid ? racc[ct][r] : 0.f);
        }
      }
    }
  };

  #pragma unroll 1
  for (int jc = 0; jc < 32; ++jc){
    const int j0 = jc * 64;
    const int D = j0 - i0;

    // ---- pos scores (writer-side rel-shift into ScW) ----
    if (D <= 960){
      posPass(0, D + 960, 0, 127, false);
    } else if (D == 1024){
      posPass(0, 1984, 0, 63, false);
      posPass(1, -65, 65, 127, true);
    } else if (D == 1088){
      posPass(1, -1, 1, 127, false);
    } else {
      posPass(1, D - 1089, 0, 127, false);
    }

    // ---- content scores: B-frags straight from kvb ----
    f32x4 cacc[4] = {};
    #pragma unroll
    for (int ks = 0; ks < 2; ++ks){
      #pragma unroll
      for (int ct = 0; ct < 4; ++ct){
        short8 bf = *(const short8*)(kvb + ((size_t)(j0 + ct * 16 + l16) * 4 + b) * 2048 + colbase + ks * 32);
        cacc[ct] = __builtin_amdgcn_mfma_f32_16x16x32_bf16(qu[ks], bf, cacc[ct], 0, 0, 0);
      }
    }

    // ---- fixed-max softmax: e = exp(s-16); own-wave LDS, no barrier ----
    #pragma unroll
    for (int ct = 0; ct < 4; ++ct){
      #pragma unroll
      for (int r = 0; r < 4; ++r){
        int gm = 16 * w + quad * 4 + r;
        int n = ct * 16 + l16;
        float sc = b2f(ScW[gm * 194 + 63 + n]);
        float s = (cacc[ct][r] + sc) * 0.125f;
        float e = __expf(s - 16.f);
        lsum[r] += e;
        Pb[gm * 72 + n] = f2b(e);
      }
    }

    // ---- PV: A-frag from own-wave Pb, B-frags straight from vtg ----
    #pragma unroll
    for (int ks = 0; ks < 2; ++ks){
      short8 af = *(short8*)&Pb[(16 * w + l16) * 72 + ks * 32 + quad * 8];
      #pragma unroll
      for (int dt = 0; dt < 4; ++dt){
        short8 bf = *(const short8*)(vtg + ((size_t)bh * 64 + dt * 16 + l16) * 2048 + j0 + ks * 32 + quad * 8);
        oacc[dt] = __builtin_amdgcn_mfma_f32_16x16x32_bf16(af, bf, oacc[dt], 0, 0, 0);
      }
    }
  }

  // ---- epilogue: reduce row sums across 16-lane groups, normalize, store ----
  #pragma unroll
  for (int r = 0; r < 4; ++r){
    float red = lsum[r];
    #pragma unroll
    for (int mk = 1; mk < 16; mk <<= 1)
      red += __shfl_xor(red, mk, 64);
    float inv = 1.f / red;
    int srow = i0 + 16 * w + quad * 4 + r;
    #pragma unroll
    for (int dt = 0; dt < 4; ++dt)
      awvb[((size_t)srow * 4 + b) * 1024 + h * 64 + dt * 16 + l16] = f2b(oacc[dt][r] * inv);
  }
}

// ---------------------------------------------------------------------------
// In-place LayerNorm over last dim (1024) of d_out.
// ---------------------------------------------------------------------------
__global__ __launch_bounds__(256) void ln_kernel(
    float* __restrict__ io, const float* __restrict__ g, const float* __restrict__ bb)
{
  const int row = blockIdx.x, t = threadIdx.x;
  float* rp = io + (size_t)row * 1024;
  float4 x = *(float4*)(rp + t * 4);
  float s  = x.x + x.y + x.z + x.w;
  float s2 = x.x*x.x + x.y*x.y + x.z*x.z + x.w*x.w;
  #pragma unroll
  for (int o = 32; o > 0; o >>= 1){
    s  += __shfl_down(s, o);
    s2 += __shfl_down(s2, o);
  }
  __shared__ float rs[4], rs2[4];
  int w = t >> 6, lane = t & 63;
  if (lane == 0){ rs[w] = s; rs2[w] = s2; }
  __syncthreads();
  s  = rs[0] + rs[1] + rs[2] + rs[3];
  s2 = rs2[0] + rs2[1] + rs2[2] + rs2[3];
  float mu   = s * (1.f/1024.f);
  float var  = s2 * (1.f/1024.f) - mu*mu;
  float rstd = rsqrtf(var + 1e-5f);
  float4 gg = *(const float4*)(g + t*4);
  float4 bv = *(const float4*)(bb + t*4);
  x.x = (x.x - mu)*rstd*gg.x + bv.x;
  x.y = (x.y - mu)*rstd*gg.y + bv.y;
  x.z = (x.z - mu)*rstd*gg.z + bv.z;
  x.w = (x.w - mu)*rstd*gg.w + bv.w;
  *(float4*)(rp + t*4) = x;
}

extern "C" void kernel_launch(void* const* d_in, const int* in_sizes, int n_in,
                              void* d_out, int out_size, void* d_ws, size_t ws_size,
                              hipStream_t stream) {
  (void)in_sizes; (void)n_in; (void)out_size; (void)ws_size;
  const float* input_ = (const float*)d_in[0];
  const float* pos    = (const float*)d_in[1];
  const float* mem    = (const float*)d_in[2];
  const float* u      = (const float*)d_in[3];
  const float* v      = (const float*)d_in[4];
  const float* Wkv    = (const float*)d_in[5];
  const float* Wq     = (const float*)d_in[6];
  const float* Wp     = (const float*)d_in[7];
  const float* Wout   = (const float*)d_in[8];
  const float* lng    = (const float*)d_in[9];
  const float* lnb    = (const float*)d_in[10];
  float* out = (float*)d_out;

  unsigned short* ws   = (unsigned short*)d_ws;
  unsigned short* xb    = ws;                               // 8192*1024
  unsigned short* posb  = xb    + (size_t)8192*1024;        // 2048*1024
  unsigned short* WkvT  = posb  + (size_t)2048*1024;        // 2048*1024
  unsigned short* WqT   = WkvT  + (size_t)2048*1024;        // 1024*1024
  unsigned short* WpT   = WqT   + (size_t)1024*1024;        // 1024*1024
  unsigned short* WoutT = WpT   + (size_t)1024*1024;        // 1024*1024
  unsigned short* kvb   = WoutT + (size_t)1024*1024;        // 8192*2048
  unsigned short* qbb   = kvb   + (size_t)8192*2048;        // 4096*1024
  unsigned short* pbb   = qbb   + (size_t)4096*1024;        // 2048*1024
  unsigned short* vtg   = pbb   + (size_t)2048*1024;        // 4096*2048
  unsigned short* awvb  = vtg   + (size_t)4096*2048;        // 4096*1024

  // convert inputs to bf16
  cvt_cat<<<8192, 256, 0, stream>>>(mem, input_, 4096*1024, 8192*1024, xb);
  cvt_cat<<<2048, 256, 0, stream>>>(pos, pos, 2048*1024, 2048*1024, posb);
  wtrans<<<dim3(64, 32), 256, 0, stream>>>(Wkv,  WkvT, 1024, 2048);
  wtrans<<<dim3(32, 32), 256, 0, stream>>>(Wq,   WqT,  1024, 1024);
  wtrans<<<dim3(32, 32), 256, 0, stream>>>(Wp,   WpT,  1024, 1024);
  wtrans<<<dim3(32, 32), 256, 0, stream>>>(Wout, WoutT,1024, 1024);

  // projections (bf16 MFMA)
  gemm_bf16<<<dim3(16, 64), 256, 0, stream>>>(xb, WkvT, 8192, 2048, 1024, nullptr, nullptr, kvb);
  gemm_bf16<<<dim3(8, 32), 256, 0, stream>>>(xb + (size_t)4096*1024, WqT, 4096, 1024, 1024, nullptr, nullptr, qbb);
  gemm_bf16<<<dim3(8, 16), 256, 0, stream>>>(posb, WpT, 2048, 1024, 1024, nullptr, nullptr, pbb);

  // V transpose for PV B-operand
  vtrans<<<dim3(32, 64), 256, 0, stream>>>(kvb, vtg);

  // zero-barrier fused rel-shift MFMA flash attention
  attn_mfma<<<dim3(16, 64), 256, 0, stream>>>(qbb, kvb, pbb, vtg, u, v, awvb);

  // out = input + awv @ W_out, then LayerNorm
  gemm_bf16<<<dim3(8, 32), 256, 0, stream>>>(awvb, WoutT, 4096, 1024, 1024, input_, out, nullptr);
  ln_kernel<<<4096, 256, 0, stream>>>(out, lng, lnb);
}

// Round 6
// 501.947 us; speedup vs baseline: 1.4656x; 1.4656x over previous
//
#include <hip/hip_runtime.h>
#include <cstdint>
#include <cstddef>

#define S_  1024
#define B_  4
#define T_  2048
#define H_  16

typedef short     short8 __attribute__((ext_vector_type(8)));
typedef float     f32x4  __attribute__((ext_vector_type(4)));
typedef unsigned short u16x8 __attribute__((ext_vector_type(8)));

__device__ __forceinline__ unsigned short f2b(float f){
  uint32_t x = __builtin_bit_cast(uint32_t, f);
  x = (x + 0x7fffu + ((x >> 16) & 1u)) >> 16;   // RNE
  return (unsigned short)x;
}
__device__ __forceinline__ float b2f(unsigned short u){
  return __builtin_bit_cast(float, ((uint32_t)u) << 16);
}

// ---------------------------------------------------------------------------
// fp32 -> bf16 convert, with 2-source concat (for x_mem = [memory; input]).
// ---------------------------------------------------------------------------
__global__ __launch_bounds__(256) void cvt_cat(
    const float* __restrict__ a, const float* __restrict__ bsrc,
    int splitElems, int total, unsigned short* __restrict__ out)
{
  int i = (blockIdx.x * 256 + threadIdx.x) * 4;
  if (i >= total) return;
  const float* src = (i < splitElems) ? (a + i) : (bsrc + (i - splitElems));
  float4 x = *(const float4*)src;
  ushort4 o;
  o.x = f2b(x.x); o.y = f2b(x.y); o.z = f2b(x.z); o.w = f2b(x.w);
  *(ushort4*)(out + i) = o;
}

// ---------------------------------------------------------------------------
// Transpose-convert: in fp32 [R][C] -> out bf16 [C][R].
// ---------------------------------------------------------------------------
__global__ __launch_bounds__(256) void wtrans(
    const float* __restrict__ in, unsigned short* __restrict__ out, int R, int C)
{
  __shared__ float tile[32][33];
  const int R0 = blockIdx.y * 32, C0 = blockIdx.x * 32;
  const int t = threadIdx.x;
  const int r = t >> 3, c4 = (t & 7) * 4;
  float4 x = *(const float4*)(in + (size_t)(R0 + r) * C + C0 + c4);
  tile[r][c4+0] = x.x; tile[r][c4+1] = x.y; tile[r][c4+2] = x.z; tile[r][c4+3] = x.w;
  __syncthreads();
  ushort4 o;
  o.x = f2b(tile[c4+0][r]); o.y = f2b(tile[c4+1][r]);
  o.z = f2b(tile[c4+2][r]); o.w = f2b(tile[c4+3][r]);
  *(ushort4*)(out + (size_t)(C0 + r) * R + R0 + c4) = o;
}

// ---------------------------------------------------------------------------
// Transpose V-half of kv into VTg[bh*64 + d][T] (bf16) for PV B-operand.
// ---------------------------------------------------------------------------
__global__ __launch_bounds__(256) void vtrans(
    const unsigned short* __restrict__ kvb, unsigned short* __restrict__ vtg)
{
  __shared__ __align__(16) unsigned short tile[64][72];
  const int t = threadIdx.x;
  const int bh = blockIdx.y;           // b*16+h
  const int b = bh >> 4, h = bh & 15;
  const int t0 = blockIdx.x * 64;
  #pragma unroll
  for (int l = 0; l < 2; ++l){
    int idx = t + l * 256;
    int row = idx >> 3, seg = (idx & 7) * 8;
    u16x8 x = *(const u16x8*)(kvb + ((size_t)(t0 + row) * 4 + b) * 2048 + 1024 + h * 64 + seg);
    *(u16x8*)&tile[row][seg] = x;
  }
  __syncthreads();
  #pragma unroll
  for (int l = 0; l < 2; ++l){
    int idx = t + l * 256;
    int d = idx >> 3, nseg = (idx & 7) * 8;
    u16x8 o;
    #pragma unroll
    for (int j = 0; j < 8; ++j) o[j] = tile[nseg + j][d];
    *(u16x8*)(vtg + ((size_t)bh * 64 + d) * 2048 + t0 + nseg) = o;
  }
}

// ---------------------------------------------------------------------------
// bf16 MFMA GEMM: C[M][N] = A[M][K] @ BT[N][K]^T. 128x128 block tile, 4 waves
// each 64x64 (4x4 tiles of 16x16x32). Optional fp32 residual, fp32/bf16 out.
// ---------------------------------------------------------------------------
__global__ __launch_bounds__(256) void gemm_bf16(
    const unsigned short* __restrict__ A, const unsigned short* __restrict__ BT,
    int M, int N, int K,
    const float* __restrict__ resid, float* __restrict__ outF,
    unsigned short* __restrict__ outB)
{
  __shared__ __align__(16) unsigned short As[128 * 72];
  __shared__ __align__(16) unsigned short Bs[128 * 72];
  const int t = threadIdx.x;
  const int M0 = blockIdx.y * 128, N0 = blockIdx.x * 128;
  const int w = t >> 6, lane = t & 63, quad = lane >> 4, l16 = lane & 15;
  const int wm = (w >> 1) * 64, wn = (w & 1) * 64;
  const int arow = t >> 1, aseg = (t & 1) * 32;

  f32x4 acc[4][4] = {};

  for (int k0 = 0; k0 < K; k0 += 64){
    __syncthreads();
    const unsigned short* ag = A  + (size_t)(M0 + arow) * K + k0 + aseg;
    const unsigned short* bg = BT + (size_t)(N0 + arow) * K + k0 + aseg;
    #pragma unroll
    for (int j = 0; j < 4; ++j){
      *(u16x8*)&As[arow * 72 + aseg + j * 8] = *(const u16x8*)(ag + j * 8);
      *(u16x8*)&Bs[arow * 72 + aseg + j * 8] = *(const u16x8*)(bg + j * 8);
    }
    __syncthreads();
    #pragma unroll
    for (int ks = 0; ks < 2; ++ks){
      short8 af[4], bf[4];
      #pragma unroll
      for (int rt = 0; rt < 4; ++rt)
        af[rt] = *(short8*)&As[(wm + rt * 16 + l16) * 72 + ks * 32 + quad * 8];
      #pragma unroll
      for (int ct = 0; ct < 4; ++ct)
        bf[ct] = *(short8*)&Bs[(wn + ct * 16 + l16) * 72 + ks * 32 + quad * 8];
      #pragma unroll
      for (int rt = 0; rt < 4; ++rt)
        #pragma unroll
        for (int ct = 0; ct < 4; ++ct)
          acc[rt][ct] = __builtin_amdgcn_mfma_f32_16x16x32_bf16(af[rt], bf[ct], acc[rt][ct], 0, 0, 0);
    }
  }

  #pragma unroll
  for (int rt = 0; rt < 4; ++rt){
    #pragma unroll
    for (int r = 0; r < 4; ++r){
      int row = M0 + wm + rt * 16 + quad * 4 + r;
      #pragma unroll
      for (int ct = 0; ct < 4; ++ct){
        int col = N0 + wn + ct * 16 + l16;
        float val = acc[rt][ct][r];
        if (resid) val += resid[(size_t)row * N + col];
        if (outF) outF[(size_t)row * N + col] = val;
        if (outB) outB[(size_t)row * N + col] = f2b(val);
      }
    }
  }
}

// ---------------------------------------------------------------------------
// MFMA flash attention with fused Transformer-XL relative shift.
// Rel-shift: delta=j-i: <=1024 -> praw[i][delta+1023]; ==1025 -> 0;
//            >=1026 -> praw[i+1][delta-1026].
// Staged-LDS structure (r4) with: A-frags (q+u / q+v) in registers,
// XOR-swizzled unpadded K/V/P tiles (conflict-free b128 frag reads,
// 49KB LDS -> 3 blocks/CU), per-wave ct-window trim (5 of 8 windows),
// single-pass composite window for the mixed D=1024 chunk (guard-zero
// rows produce the delta==1025 zeros), writer-side shift scatter into
// bf16 Sc, fixed-max softmax exp(s-16). 2 barriers per chunk.
// ---------------------------------------------------------------------------
__global__ __launch_bounds__(256, 3) void attn_mfma(
    const unsigned short* __restrict__ qb,   // (4096,1024) bf16
    const unsigned short* __restrict__ kvb,  // (8192,2048) bf16 [k|v]
    const unsigned short* __restrict__ pbm,  // (2048,1024) bf16
    const unsigned short* __restrict__ vtg,  // (64*64, 2048) bf16 V^T per (b,h)
    const float* __restrict__ ub, const float* __restrict__ vb,
    unsigned short* __restrict__ awvb)       // (4096,1024) bf16
{
  __shared__ __align__(16) unsigned short Kc[64 * 64];   // swizzled
  __shared__ __align__(16) unsigned short VT[64 * 64];   // swizzled
  __shared__ __align__(16) unsigned short Pw[128 * 64];  // swizzled
  __shared__ __align__(16) unsigned short Pb[64 * 72];   // padded (scalar writes)
  __shared__ unsigned short Sc[64 * 65];                 // shifted pos scores (bf16)

  const int t = threadIdx.x;
  const int i0 = blockIdx.x * 64;
  const int bh = blockIdx.y;
  const int b = bh >> 4, h = bh & 15;
  const int w = t >> 6, lane = t & 63, quad = lane >> 4, l16 = lane & 15;
  const int colbase = h * 64 + quad * 8;
  const int ctLo = 3 - w;                    // wave-trimmed window range [ctLo, ctLo+4]

  // ---- register A-fragments: qu[ks], qv[cs][ks] (wave rows 16w+l16(+cs)) ----
  short8 qu[2], qv[2][2];
  #pragma unroll
  for (int cs = 0; cs < 2; ++cs){
    int gr = i0 + 16 * w + l16 + cs;         // gr==1024 possible: OOB into ws, masked later
    #pragma unroll
    for (int ks = 0; ks < 2; ++ks){
      u16x8 q8 = *(const u16x8*)(qb + ((size_t)gr * 4 + b) * 1024 + colbase + ks * 32);
      #pragma unroll
      for (int j = 0; j < 8; ++j){
        float f = b2f(q8[j]);
        qv[cs][ks][j] = (short)f2b(f + vb[colbase + ks * 32 + j]);
        if (cs == 0) qu[ks][j] = (short)f2b(f + ub[colbase + ks * 32 + j]);
      }
    }
  }

  f32x4 oacc[4] = {};                        // [d-tile], rows = quad*4+r
  float lsum[4] = {0.f, 0.f, 0.f, 0.f};

  #pragma unroll 1
  for (int jc = 0; jc < 32; ++jc){
    const int j0 = jc * 64;
    const int D = j0 - i0;

    __syncthreads();                         // (1) prev chunk's LDS reads done

    // ---- stage K and V^T (XOR-swizzled 16B blocks) ----
    #pragma unroll
    for (int l = 0; l < 2; ++l){
      int idx = t + l * 256;
      int row = idx >> 3, cb = idx & 7;
      int sw = (cb ^ (row & 7)) * 8;
      *(u16x8*)&Kc[row * 64 + sw] =
          *(const u16x8*)(kvb + ((size_t)(j0 + row) * 4 + b) * 2048 + h * 64 + cb * 8);
      *(u16x8*)&VT[row * 64 + sw] =
          *(const u16x8*)(vtg + ((size_t)bh * 64 + row) * 2048 + j0 + cb * 8);
    }
    // ---- stage pos window (composite for D==1024) ----
    #pragma unroll
    for (int l = 0; l < 4; ++l){
      int idx = t + l * 256;
      int row = idx >> 3, cb = idx & 7;
      int pr;
      if (D <= 960)          pr = D + 960 + row;
      else if (D == 1024)    pr = (row < 64) ? (1984 + row) : (row - 65);
      else                   pr = D - 1089 + row;
      u16x8 x;
      if (pr >= 0 && pr < T_){
        x = *(const u16x8*)(pbm + (size_t)pr * 1024 + h * 64 + cb * 8);
      } else {
        for (int j = 0; j < 8; ++j) x[j] = 0;
      }
      *(u16x8*)&Pw[row * 64 + ((cb ^ (row & 7)) * 8)] = x;
    }
    __syncthreads();                         // (2) staging visible

    // ---- pos scores: 5 trimmed windows, writer-side shift scatter ----
    #pragma unroll
    for (int ci = 0; ci < 5; ++ci){
      int ct = ctLo + ci;
      int cs = (D <= 960) ? 0 : ((D >= 1088) ? 1 : ((ct >= 4) ? 1 : 0));
      f32x4 racc = {};
      #pragma unroll
      for (int ks = 0; ks < 2; ++ks){
        int rr = ct * 16 + l16;
        short8 bf = *(short8*)&Pw[rr * 64 + (((ks * 4 + quad) ^ (rr & 7)) * 8)];
        racc = __builtin_amdgcn_mfma_f32_16x16x32_bf16(qv[cs][ks], bf, racc, 0, 0, 0);
      }
      int c = ct * 16 + l16;
      #pragma unroll
      for (int r = 0; r < 4; ++r){
        int gm = 16 * w + quad * 4 + r;
        int n = c + gm - 63;
        if ((unsigned)n < 64u) Sc[gm * 65 + n] = f2b(racc[r]);
      }
    }

    // ---- content scores ----
    f32x4 cacc[4] = {};
    #pragma unroll
    for (int ks = 0; ks < 2; ++ks){
      #pragma unroll
      for (int ct = 0; ct < 4; ++ct){
        int rr = ct * 16 + l16;
        short8 bf = *(short8*)&Kc[rr * 64 + (((ks * 4 + quad) ^ (rr & 7)) * 8)];
        cacc[ct] = __builtin_amdgcn_mfma_f32_16x16x32_bf16(qu[ks], bf, cacc[ct], 0, 0, 0);
      }
    }

    // ---- fixed-max softmax: e = exp(s-16); own-wave LDS rows ----
    #pragma unroll
    for (int ct = 0; ct < 4; ++ct){
      #pragma unroll
      for (int r = 0; r < 4; ++r){
        int gm = 16 * w + quad * 4 + r;
        int n = ct * 16 + l16;
        float s = (cacc[ct][r] + b2f(Sc[gm * 65 + n])) * 0.125f;
        float e = __expf(s - 16.f);
        lsum[r] += e;
        Pb[gm * 72 + n] = f2b(e);
      }
    }

    // ---- PV: A-frag from own-wave Pb, B-frag from swizzled VT ----
    #pragma unroll
    for (int ks = 0; ks < 2; ++ks){
      short8 af = *(short8*)&Pb[(16 * w + l16) * 72 + ks * 32 + quad * 8];
      #pragma unroll
      for (int dt = 0; dt < 4; ++dt){
        int rr = dt * 16 + l16;
        short8 bf = *(short8*)&VT[rr * 64 + (((ks * 4 + quad) ^ (rr & 7)) * 8)];
        oacc[dt] = __builtin_amdgcn_mfma_f32_16x16x32_bf16(af, bf, oacc[dt], 0, 0, 0);
      }
    }
  }

  // ---- epilogue: reduce row sums across 16-lane groups, normalize, store ----
  #pragma unroll
  for (int r = 0; r < 4; ++r){
    float red = lsum[r];
    #pragma unroll
    for (int mk = 1; mk < 16; mk <<= 1)
      red += __shfl_xor(red, mk, 64);
    float inv = 1.f / red;
    int srow = i0 + 16 * w + quad * 4 + r;
    #pragma unroll
    for (int dt = 0; dt < 4; ++dt)
      awvb[((size_t)srow * 4 + b) * 1024 + h * 64 + dt * 16 + l16] = f2b(oacc[dt][r] * inv);
  }
}

// ---------------------------------------------------------------------------
// In-place LayerNorm over last dim (1024) of d_out.
// ---------------------------------------------------------------------------
__global__ __launch_bounds__(256) void ln_kernel(
    float* __restrict__ io, const float* __restrict__ g, const float* __restrict__ bb)
{
  const int row = blockIdx.x, t = threadIdx.x;
  float* rp = io + (size_t)row * 1024;
  float4 x = *(float4*)(rp + t * 4);
  float s  = x.x + x.y + x.z + x.w;
  float s2 = x.x*x.x + x.y*x.y + x.z*x.z + x.w*x.w;
  #pragma unroll
  for (int o = 32; o > 0; o >>= 1){
    s  += __shfl_down(s, o);
    s2 += __shfl_down(s2, o);
  }
  __shared__ float rs[4], rs2[4];
  int w = t >> 6, lane = t & 63;
  if (lane == 0){ rs[w] = s; rs2[w] = s2; }
  __syncthreads();
  s  = rs[0] + rs[1] + rs[2] + rs[3];
  s2 = rs2[0] + rs2[1] + rs2[2] + rs2[3];
  float mu   = s * (1.f/1024.f);
  float var  = s2 * (1.f/1024.f) - mu*mu;
  float rstd = rsqrtf(var + 1e-5f);
  float4 gg = *(const float4*)(g + t*4);
  float4 bv = *(const float4*)(bb + t*4);
  x.x = (x.x - mu)*rstd*gg.x + bv.x;
  x.y = (x.y - mu)*rstd*gg.y + bv.y;
  x.z = (x.z - mu)*rstd*gg.z + bv.z;
  x.w = (x.w - mu)*rstd*gg.w + bv.w;
  *(float4*)(rp + t*4) = x;
}

extern "C" void kernel_launch(void* const* d_in, const int* in_sizes, int n_in,
                              void* d_out, int out_size, void* d_ws, size_t ws_size,
                              hipStream_t stream) {
  (void)in_sizes; (void)n_in; (void)out_size; (void)ws_size;
  const float* input_ = (const float*)d_in[0];
  const float* pos    = (const float*)d_in[1];
  const float* mem    = (const float*)d_in[2];
  const float* u      = (const float*)d_in[3];
  const float* v      = (const float*)d_in[4];
  const float* Wkv    = (const float*)d_in[5];
  const float* Wq     = (const float*)d_in[6];
  const float* Wp     = (const float*)d_in[7];
  const float* Wout   = (const float*)d_in[8];
  const float* lng    = (const float*)d_in[9];
  const float* lnb    = (const float*)d_in[10];
  float* out = (float*)d_out;

  unsigned short* ws   = (unsigned short*)d_ws;
  unsigned short* xb    = ws;                               // 8192*1024
  unsigned short* posb  = xb    + (size_t)8192*1024;        // 2048*1024
  unsigned short* WkvT  = posb  + (size_t)2048*1024;        // 2048*1024
  unsigned short* WqT   = WkvT  + (size_t)2048*1024;        // 1024*1024
  unsigned short* WpT   = WqT   + (size_t)1024*1024;        // 1024*1024
  unsigned short* WoutT = WpT   + (size_t)1024*1024;        // 1024*1024
  unsigned short* kvb   = WoutT + (size_t)1024*1024;        // 8192*2048
  unsigned short* qbb   = kvb   + (size_t)8192*2048;        // 4096*1024
  unsigned short* pbb   = qbb   + (size_t)4096*1024;        // 2048*1024
  unsigned short* vtg   = pbb   + (size_t)2048*1024;        // 4096*2048
  unsigned short* awvb  = vtg   + (size_t)4096*2048;        // 4096*1024

  // convert inputs to bf16
  cvt_cat<<<8192, 256, 0, stream>>>(mem, input_, 4096*1024, 8192*1024, xb);
  cvt_cat<<<2048, 256, 0, stream>>>(pos, pos, 2048*1024, 2048*1024, posb);
  wtrans<<<dim3(64, 32), 256, 0, stream>>>(Wkv,  WkvT, 1024, 2048);
  wtrans<<<dim3(32, 32), 256, 0, stream>>>(Wq,   WqT,  1024, 1024);
  wtrans<<<dim3(32, 32), 256, 0, stream>>>(Wp,   WpT,  1024, 1024);
  wtrans<<<dim3(32, 32), 256, 0, stream>>>(Wout, WoutT,1024, 1024);

  // projections (bf16 MFMA)
  gemm_bf16<<<dim3(16, 64), 256, 0, stream>>>(xb, WkvT, 8192, 2048, 1024, nullptr, nullptr, kvb);
  gemm_bf16<<<dim3(8, 32), 256, 0, stream>>>(xb + (size_t)4096*1024, WqT, 4096, 1024, 1024, nullptr, nullptr, qbb);
  gemm_bf16<<<dim3(8, 16), 256, 0, stream>>>(posb, WpT, 2048, 1024, 1024, nullptr, nullptr, pbb);

  // V transpose for PV B-operand
  vtrans<<<dim3(32, 64), 256, 0, stream>>>(kvb, vtg);

  // fused rel-shift MFMA flash attention
  attn_mfma<<<dim3(16, 64), 256, 0, stream>>>(qbb, kvb, pbb, vtg, u, v, awvb);

  // out = input + awv @ W_out, then LayerNorm
  gemm_bf16<<<dim3(8, 32), 256, 0, stream>>>(awvb, WoutT, 4096, 1024, 1024, input_, out, nullptr);
  ln_kernel<<<4096, 256, 0, stream>>>(out, lng, lnb);
}

// Round 7
// 492.493 us; speedup vs baseline: 1.4938x; 1.0192x over previous
//
#include <hip/hip_runtime.h>
#include <cstdint>
#include <cstddef>

#define S_  1024
#define B_  4
#define T_  2048
#define H_  16

typedef short     short8 __attribute__((ext_vector_type(8)));
typedef float     f32x4  __attribute__((ext_vector_type(4)));
typedef unsigned short u16x8 __attribute__((ext_vector_type(8)));

__device__ __forceinline__ unsigned short f2b(float f){
  uint32_t x = __builtin_bit_cast(uint32_t, f);
  x = (x + 0x7fffu + ((x >> 16) & 1u)) >> 16;   // RNE
  return (unsigned short)x;
}
__device__ __forceinline__ float b2f(unsigned short u){
  return __builtin_bit_cast(float, ((uint32_t)u) << 16);
}

// async global->LDS, 16B per lane; lds dest must be wave-uniform base
__device__ __forceinline__ void gl_lds16(const unsigned short* g, unsigned short* l){
  __builtin_amdgcn_global_load_lds(
      (const __attribute__((address_space(1))) void*)g,
      (__attribute__((address_space(3))) void*)l,
      16, 0, 0);
}

// ---------------------------------------------------------------------------
// fp32 -> bf16 convert, with 2-source concat (for x_mem = [memory; input]).
// ---------------------------------------------------------------------------
__global__ __launch_bounds__(256) void cvt_cat(
    const float* __restrict__ a, const float* __restrict__ bsrc,
    int splitElems, int total, unsigned short* __restrict__ out)
{
  int i = (blockIdx.x * 256 + threadIdx.x) * 4;
  if (i >= total) return;
  const float* src = (i < splitElems) ? (a + i) : (bsrc + (i - splitElems));
  float4 x = *(const float4*)src;
  ushort4 o;
  o.x = f2b(x.x); o.y = f2b(x.y); o.z = f2b(x.z); o.w = f2b(x.w);
  *(ushort4*)(out + i) = o;
}

// ---------------------------------------------------------------------------
// Transpose-convert: in fp32 [R][C] -> out bf16 [C][R].
// ---------------------------------------------------------------------------
__global__ __launch_bounds__(256) void wtrans(
    const float* __restrict__ in, unsigned short* __restrict__ out, int R, int C)
{
  __shared__ float tile[32][33];
  const int R0 = blockIdx.y * 32, C0 = blockIdx.x * 32;
  const int t = threadIdx.x;
  const int r = t >> 3, c4 = (t & 7) * 4;
  float4 x = *(const float4*)(in + (size_t)(R0 + r) * C + C0 + c4);
  tile[r][c4+0] = x.x; tile[r][c4+1] = x.y; tile[r][c4+2] = x.z; tile[r][c4+3] = x.w;
  __syncthreads();
  ushort4 o;
  o.x = f2b(tile[c4+0][r]); o.y = f2b(tile[c4+1][r]);
  o.z = f2b(tile[c4+2][r]); o.w = f2b(tile[c4+3][r]);
  *(ushort4*)(out + (size_t)(C0 + r) * R + R0 + c4) = o;
}

// ---------------------------------------------------------------------------
// Transpose V-half of kv into VTg[bh*64 + d][T] (bf16) for PV B-operand.
// ---------------------------------------------------------------------------
__global__ __launch_bounds__(256) void vtrans(
    const unsigned short* __restrict__ kvb, unsigned short* __restrict__ vtg)
{
  __shared__ __align__(16) unsigned short tile[64][72];
  const int t = threadIdx.x;
  const int bh = blockIdx.y;           // b*16+h
  const int b = bh >> 4, h = bh & 15;
  const int t0 = blockIdx.x * 64;
  #pragma unroll
  for (int l = 0; l < 2; ++l){
    int idx = t + l * 256;
    int row = idx >> 3, seg = (idx & 7) * 8;
    u16x8 x = *(const u16x8*)(kvb + ((size_t)(t0 + row) * 4 + b) * 2048 + 1024 + h * 64 + seg);
    *(u16x8*)&tile[row][seg] = x;
  }
  __syncthreads();
  #pragma unroll
  for (int l = 0; l < 2; ++l){
    int idx = t + l * 256;
    int d = idx >> 3, nseg = (idx & 7) * 8;
    u16x8 o;
    #pragma unroll
    for (int j = 0; j < 8; ++j) o[j] = tile[nseg + j][d];
    *(u16x8*)(vtg + ((size_t)bh * 64 + d) * 2048 + t0 + nseg) = o;
  }
}

// ---------------------------------------------------------------------------
// bf16 MFMA GEMM with async global->LDS staging (m97 pattern, width=16).
// C[M][N] = A[M][K] @ BT[N][K]^T. 128x128 tile, BK=64, 4 waves of 64x64.
// LDS layout (DMA-linear): element (row,k) at blk*512 + cb*64 + r*8 + (k&7),
// blk=row>>3, cb=k>>3, r=row&7  ->  frag reads are contiguous 16B, banks
// spread by r (rows r, r+8 alias 2-way = free).
// ---------------------------------------------------------------------------
#define AS_IDX(row,k) ((((row) >> 3) * 512) + (((k) >> 3) * 64) + (((row) & 7) * 8) + ((k) & 7))

__global__ __launch_bounds__(256) void gemm_bf16(
    const unsigned short* __restrict__ A, const unsigned short* __restrict__ BT,
    int M, int N, int K,
    const float* __restrict__ resid, float* __restrict__ outF,
    unsigned short* __restrict__ outB)
{
  __shared__ __align__(16) unsigned short As[128 * 64];
  __shared__ __align__(16) unsigned short Bs[128 * 64];
  const int t = threadIdx.x;
  const int M0 = blockIdx.y * 128, N0 = blockIdx.x * 128;
  const int w = t >> 6, lane = t & 63, quad = lane >> 4, l16 = lane & 15;
  const int wm = (w >> 1) * 64, wn = (w & 1) * 64;
  const int lr = lane & 7, lcb = lane >> 3;      // staging: lane -> (row-in-8blk, colblk)

  f32x4 acc[4][4] = {};

  for (int k0 = 0; k0 < K; k0 += 64){
    __syncthreads();
    #pragma unroll
    for (int i = 0; i < 4; ++i){
      int blk = 4 * w + i;                       // 8-row block of the 128-row tile
      gl_lds16(A  + (size_t)(M0 + 8 * blk + lr) * K + k0 + lcb * 8, As + blk * 512);
      gl_lds16(BT + (size_t)(N0 + 8 * blk + lr) * K + k0 + lcb * 8, Bs + blk * 512);
    }
    __syncthreads();                             // drains vmcnt -> LDS visible
    #pragma unroll
    for (int ks = 0; ks < 2; ++ks){
      short8 af[4], bf[4];
      #pragma unroll
      for (int rt = 0; rt < 4; ++rt)
        af[rt] = *(short8*)&As[AS_IDX(wm + rt * 16 + l16, ks * 32 + quad * 8)];
      #pragma unroll
      for (int ct = 0; ct < 4; ++ct)
        bf[ct] = *(short8*)&Bs[AS_IDX(wn + ct * 16 + l16, ks * 32 + quad * 8)];
      #pragma unroll
      for (int rt = 0; rt < 4; ++rt)
        #pragma unroll
        for (int ct = 0; ct < 4; ++ct)
          acc[rt][ct] = __builtin_amdgcn_mfma_f32_16x16x32_bf16(af[rt], bf[ct], acc[rt][ct], 0, 0, 0);
    }
  }

  #pragma unroll
  for (int rt = 0; rt < 4; ++rt){
    #pragma unroll
    for (int r = 0; r < 4; ++r){
      int row = M0 + wm + rt * 16 + quad * 4 + r;
      #pragma unroll
      for (int ct = 0; ct < 4; ++ct){
        int col = N0 + wn + ct * 16 + l16;
        float val = acc[rt][ct][r];
        if (resid) val += resid[(size_t)row * N + col];
        if (outF) outF[(size_t)row * N + col] = val;
        if (outB) outB[(size_t)row * N + col] = f2b(val);
      }
    }
  }
}

// ---------------------------------------------------------------------------
// MFMA flash attention with fused Transformer-XL relative shift.
// Rel-shift: delta=j-i: <=1024 -> praw[i][delta+1023]; ==1025 -> 0;
//            >=1026 -> praw[i+1][delta-1026].
// r6 staged structure + register prefetch pipeline: chunk jc+1's global
// staging loads are issued into VGPRs during chunk jc's compute, so global
// latency is off the barrier-to-barrier critical path. 2 barriers/chunk.
// ---------------------------------------------------------------------------
__global__ __launch_bounds__(256, 3) void attn_mfma(
    const unsigned short* __restrict__ qb,   // (4096,1024) bf16
    const unsigned short* __restrict__ kvb,  // (8192,2048) bf16 [k|v]
    const unsigned short* __restrict__ pbm,  // (2048,1024) bf16
    const unsigned short* __restrict__ vtg,  // (64*64, 2048) bf16 V^T per (b,h)
    const float* __restrict__ ub, const float* __restrict__ vb,
    unsigned short* __restrict__ awvb)       // (4096,1024) bf16
{
  __shared__ __align__(16) unsigned short Kc[64 * 64];   // swizzled
  __shared__ __align__(16) unsigned short VT[64 * 64];   // swizzled
  __shared__ __align__(16) unsigned short Pw[128 * 64];  // swizzled
  __shared__ __align__(16) unsigned short Pb[64 * 72];   // padded (scalar writes)
  __shared__ unsigned short Sc[64 * 65];                 // shifted pos scores (bf16)

  const int t = threadIdx.x;
  const int i0 = blockIdx.x * 64;
  const int bh = blockIdx.y;
  const int b = bh >> 4, h = bh & 15;
  const int w = t >> 6, lane = t & 63, quad = lane >> 4, l16 = lane & 15;
  const int colbase = h * 64 + quad * 8;
  const int ctLo = 3 - w;                    // wave-trimmed window range [ctLo, ctLo+4]

  // ---- register A-fragments: qu[ks], qv[cs][ks] (wave rows 16w+l16(+cs)) ----
  short8 qu[2], qv[2][2];
  #pragma unroll
  for (int cs = 0; cs < 2; ++cs){
    int gr = i0 + 16 * w + l16 + cs;         // gr==1024 possible: OOB into ws, masked later
    #pragma unroll
    for (int ks = 0; ks < 2; ++ks){
      u16x8 q8 = *(const u16x8*)(qb + ((size_t)gr * 4 + b) * 1024 + colbase + ks * 32);
      #pragma unroll
      for (int j = 0; j < 8; ++j){
        float f = b2f(q8[j]);
        qv[cs][ks][j] = (short)f2b(f + vb[colbase + ks * 32 + j]);
        if (cs == 0) qu[ks][j] = (short)f2b(f + ub[colbase + ks * 32 + j]);
      }
    }
  }

  f32x4 oacc[4] = {};                        // [d-tile], rows = quad*4+r
  float lsum[4] = {0.f, 0.f, 0.f, 0.f};

  // staging prefetch registers
  u16x8 pk[2], pv2[2], pp[4];

  auto loadRegs = [&](int jc){
    const int j0 = jc * 64;
    const int D = j0 - i0;
    #pragma unroll
    for (int l = 0; l < 2; ++l){
      int idx = t + l * 256;
      int row = idx >> 3, cb = idx & 7;
      pk[l]  = *(const u16x8*)(kvb + ((size_t)(j0 + row) * 4 + b) * 2048 + h * 64 + cb * 8);
      pv2[l] = *(const u16x8*)(vtg + ((size_t)bh * 64 + row) * 2048 + j0 + cb * 8);
    }
    #pragma unroll
    for (int l = 0; l < 4; ++l){
      int idx = t + l * 256;
      int row = idx >> 3, cb = idx & 7;
      int pr;
      if (D <= 960)          pr = D + 960 + row;
      else if (D == 1024)    pr = (row < 64) ? (1984 + row) : (row - 65);
      else                   pr = D - 1089 + row;
      u16x8 x;
      if (pr >= 0 && pr < T_){
        x = *(const u16x8*)(pbm + (size_t)pr * 1024 + h * 64 + cb * 8);
      } else {
        for (int j = 0; j < 8; ++j) x[j] = 0;
      }
      pp[l] = x;
    }
  };

  auto storeRegs = [&](){
    #pragma unroll
    for (int l = 0; l < 2; ++l){
      int idx = t + l * 256;
      int row = idx >> 3, cb = idx & 7;
      int sw = (cb ^ (row & 7)) * 8;
      *(u16x8*)&Kc[row * 64 + sw] = pk[l];
      *(u16x8*)&VT[row * 64 + sw] = pv2[l];
    }
    #pragma unroll
    for (int l = 0; l < 4; ++l){
      int idx = t + l * 256;
      int row = idx >> 3, cb = idx & 7;
      *(u16x8*)&Pw[row * 64 + ((cb ^ (row & 7)) * 8)] = pp[l];
    }
  };

  loadRegs(0);

  #pragma unroll 1
  for (int jc = 0; jc < 32; ++jc){
    const int j0 = jc * 64;
    const int D = j0 - i0;

    __syncthreads();                         // (1) prev chunk's LDS reads done
    storeRegs();
    if (jc < 31) loadRegs(jc + 1);           // prefetch next chunk during compute
    __syncthreads();                         // (2) staging visible

    // ---- pos scores: 5 trimmed windows, writer-side shift scatter ----
    #pragma unroll
    for (int ci = 0; ci < 5; ++ci){
      int ct = ctLo + ci;
      int cs = (D <= 960) ? 0 : ((D >= 1088) ? 1 : ((ct >= 4) ? 1 : 0));
      f32x4 racc = {};
      #pragma unroll
      for (int ks = 0; ks < 2; ++ks){
        int rr = ct * 16 + l16;
        short8 bf = *(short8*)&Pw[rr * 64 + (((ks * 4 + quad) ^ (rr & 7)) * 8)];
        racc = __builtin_amdgcn_mfma_f32_16x16x32_bf16(qv[cs][ks], bf, racc, 0, 0, 0);
      }
      int c = ct * 16 + l16;
      #pragma unroll
      for (int r = 0; r < 4; ++r){
        int gm = 16 * w + quad * 4 + r;
        int n = c + gm - 63;
        if ((unsigned)n < 64u) Sc[gm * 65 + n] = f2b(racc[r]);
      }
    }

    // ---- content scores ----
    f32x4 cacc[4] = {};
    #pragma unroll
    for (int ks = 0; ks < 2; ++ks){
      #pragma unroll
      for (int ct = 0; ct < 4; ++ct){
        int rr = ct * 16 + l16;
        short8 bf = *(short8*)&Kc[rr * 64 + (((ks * 4 + quad) ^ (rr & 7)) * 8)];
        cacc[ct] = __builtin_amdgcn_mfma_f32_16x16x32_bf16(qu[ks], bf, cacc[ct], 0, 0, 0);
      }
    }

    // ---- fixed-max softmax: e = exp(s-16); own-wave LDS rows ----
    #pragma unroll
    for (int ct = 0; ct < 4; ++ct){
      #pragma unroll
      for (int r = 0; r < 4; ++r){
        int gm = 16 * w + quad * 4 + r;
        int n = ct * 16 + l16;
        float s = (cacc[ct][r] + b2f(Sc[gm * 65 + n])) * 0.125f;
        float e = __expf(s - 16.f);
        lsum[r] += e;
        Pb[gm * 72 + n] = f2b(e);
      }
    }

    // ---- PV: A-frag from own-wave Pb, B-frag from swizzled VT ----
    #pragma unroll
    for (int ks = 0; ks < 2; ++ks){
      short8 af = *(short8*)&Pb[(16 * w + l16) * 72 + ks * 32 + quad * 8];
      #pragma unroll
      for (int dt = 0; dt < 4; ++dt){
        int rr = dt * 16 + l16;
        short8 bf = *(short8*)&VT[rr * 64 + (((ks * 4 + quad) ^ (rr & 7)) * 8)];
        oacc[dt] = __builtin_amdgcn_mfma_f32_16x16x32_bf16(af, bf, oacc[dt], 0, 0, 0);
      }
    }
  }

  // ---- epilogue: reduce row sums across 16-lane groups, normalize, store ----
  #pragma unroll
  for (int r = 0; r < 4; ++r){
    float red = lsum[r];
    #pragma unroll
    for (int mk = 1; mk < 16; mk <<= 1)
      red += __shfl_xor(red, mk, 64);
    float inv = 1.f / red;
    int srow = i0 + 16 * w + quad * 4 + r;
    #pragma unroll
    for (int dt = 0; dt < 4; ++dt)
      awvb[((size_t)srow * 4 + b) * 1024 + h * 64 + dt * 16 + l16] = f2b(oacc[dt][r] * inv);
  }
}

// ---------------------------------------------------------------------------
// In-place LayerNorm over last dim (1024) of d_out.
// ---------------------------------------------------------------------------
__global__ __launch_bounds__(256) void ln_kernel(
    float* __restrict__ io, const float* __restrict__ g, const float* __restrict__ bb)
{
  const int row = blockIdx.x, t = threadIdx.x;
  float* rp = io + (size_t)row * 1024;
  float4 x = *(float4*)(rp + t * 4);
  float s  = x.x + x.y + x.z + x.w;
  float s2 = x.x*x.x + x.y*x.y + x.z*x.z + x.w*x.w;
  #pragma unroll
  for (int o = 32; o > 0; o >>= 1){
    s  += __shfl_down(s, o);
    s2 += __shfl_down(s2, o);
  }
  __shared__ float rs[4], rs2[4];
  int w = t >> 6, lane = t & 63;
  if (lane == 0){ rs[w] = s; rs2[w] = s2; }
  __syncthreads();
  s  = rs[0] + rs[1] + rs[2] + rs[3];
  s2 = rs2[0] + rs2[1] + rs2[2] + rs2[3];
  float mu   = s * (1.f/1024.f);
  float var  = s2 * (1.f/1024.f) - mu*mu;
  float rstd = rsqrtf(var + 1e-5f);
  float4 gg = *(const float4*)(g + t*4);
  float4 bv = *(const float4*)(bb + t*4);
  x.x = (x.x - mu)*rstd*gg.x + bv.x;
  x.y = (x.y - mu)*rstd*gg.y + bv.y;
  x.z = (x.z - mu)*rstd*gg.z + bv.z;
  x.w = (x.w - mu)*rstd*gg.w + bv.w;
  *(float4*)(rp + t*4) = x;
}

extern "C" void kernel_launch(void* const* d_in, const int* in_sizes, int n_in,
                              void* d_out, int out_size, void* d_ws, size_t ws_size,
                              hipStream_t stream) {
  (void)in_sizes; (void)n_in; (void)out_size; (void)ws_size;
  const float* input_ = (const float*)d_in[0];
  const float* pos    = (const float*)d_in[1];
  const float* mem    = (const float*)d_in[2];
  const float* u      = (const float*)d_in[3];
  const float* v      = (const float*)d_in[4];
  const float* Wkv    = (const float*)d_in[5];
  const float* Wq     = (const float*)d_in[6];
  const float* Wp     = (const float*)d_in[7];
  const float* Wout   = (const float*)d_in[8];
  const float* lng    = (const float*)d_in[9];
  const float* lnb    = (const float*)d_in[10];
  float* out = (float*)d_out;

  unsigned short* ws   = (unsigned short*)d_ws;
  unsigned short* xb    = ws;                               // 8192*1024
  unsigned short* posb  = xb    + (size_t)8192*1024;        // 2048*1024
  unsigned short* WkvT  = posb  + (size_t)2048*1024;        // 2048*1024
  unsigned short* WqT   = WkvT  + (size_t)2048*1024;        // 1024*1024
  unsigned short* WpT   = WqT   + (size_t)1024*1024;        // 1024*1024
  unsigned short* WoutT = WpT   + (size_t)1024*1024;        // 1024*1024
  unsigned short* kvb   = WoutT + (size_t)1024*1024;        // 8192*2048
  unsigned short* qbb   = kvb   + (size_t)8192*2048;        // 4096*1024
  unsigned short* pbb   = qbb   + (size_t)4096*1024;        // 2048*1024
  unsigned short* vtg   = pbb   + (size_t)2048*1024;        // 4096*2048
  unsigned short* awvb  = vtg   + (size_t)4096*2048;        // 4096*1024

  // convert inputs to bf16
  cvt_cat<<<8192, 256, 0, stream>>>(mem, input_, 4096*1024, 8192*1024, xb);
  cvt_cat<<<2048, 256, 0, stream>>>(pos, pos, 2048*1024, 2048*1024, posb);
  wtrans<<<dim3(64, 32), 256, 0, stream>>>(Wkv,  WkvT, 1024, 2048);
  wtrans<<<dim3(32, 32), 256, 0, stream>>>(Wq,   WqT,  1024, 1024);
  wtrans<<<dim3(32, 32), 256, 0, stream>>>(Wp,   WpT,  1024, 1024);
  wtrans<<<dim3(32, 32), 256, 0, stream>>>(Wout, WoutT,1024, 1024);

  // projections (bf16 MFMA, async-staged)
  gemm_bf16<<<dim3(16, 64), 256, 0, stream>>>(xb, WkvT, 8192, 2048, 1024, nullptr, nullptr, kvb);
  gemm_bf16<<<dim3(8, 32), 256, 0, stream>>>(xb + (size_t)4096*1024, WqT, 4096, 1024, 1024, nullptr, nullptr, qbb);
  gemm_bf16<<<dim3(8, 16), 256, 0, stream>>>(posb, WpT, 2048, 1024, 1024, nullptr, nullptr, pbb);

  // V transpose for PV B-operand
  vtrans<<<dim3(32, 64), 256, 0, stream>>>(kvb, vtg);

  // fused rel-shift MFMA flash attention (register-prefetch pipeline)
  attn_mfma<<<dim3(16, 64), 256, 0, stream>>>(qbb, kvb, pbb, vtg, u, v, awvb);

  // out = input + awv @ W_out, then LayerNorm
  gemm_bf16<<<dim3(8, 32), 256, 0, stream>>>(awvb, WoutT, 4096, 1024, 1024, input_, out, nullptr);
  ln_kernel<<<4096, 256, 0, stream>>>(out, lng, lnb);
}

// Round 8
// 405.296 us; speedup vs baseline: 1.8151x; 1.2151x over previous
//
#include <hip/hip_runtime.h>
#include <cstdint>
#include <cstddef>

#define S_  1024
#define B_  4
#define T_  2048
#define H_  16

typedef short     short8 __attribute__((ext_vector_type(8)));
typedef float     f32x4  __attribute__((ext_vector_type(4)));
typedef unsigned short u16x8 __attribute__((ext_vector_type(8)));

__device__ __forceinline__ unsigned short f2b(float f){
  uint32_t x = __builtin_bit_cast(uint32_t, f);
  x = (x + 0x7fffu + ((x >> 16) & 1u)) >> 16;   // RNE
  return (unsigned short)x;
}
__device__ __forceinline__ unsigned short f2bt(float f){   // truncate (1 op)
  return (unsigned short)(__builtin_bit_cast(uint32_t, f) >> 16);
}
__device__ __forceinline__ float b2f(unsigned short u){
  return __builtin_bit_cast(float, ((uint32_t)u) << 16);
}

// async global->LDS, 16B per lane; lds dest must be wave-uniform base
__device__ __forceinline__ void gl_lds16(const unsigned short* g, unsigned short* l){
  __builtin_amdgcn_global_load_lds(
      (const __attribute__((address_space(1))) void*)g,
      (__attribute__((address_space(3))) void*)l,
      16, 0, 0);
}

// ---------------------------------------------------------------------------
// fp32 -> bf16 convert, with 2-source concat (for x_mem = [memory; input]).
// ---------------------------------------------------------------------------
__global__ __launch_bounds__(256) void cvt_cat(
    const float* __restrict__ a, const float* __restrict__ bsrc,
    int splitElems, int total, unsigned short* __restrict__ out)
{
  int i = (blockIdx.x * 256 + threadIdx.x) * 4;
  if (i >= total) return;
  const float* src = (i < splitElems) ? (a + i) : (bsrc + (i - splitElems));
  float4 x = *(const float4*)src;
  ushort4 o;
  o.x = f2b(x.x); o.y = f2b(x.y); o.z = f2b(x.z); o.w = f2b(x.w);
  *(ushort4*)(out + i) = o;
}

// ---------------------------------------------------------------------------
// Transpose-convert: in fp32 [R][C] -> out bf16 [C][R].
// ---------------------------------------------------------------------------
__global__ __launch_bounds__(256) void wtrans(
    const float* __restrict__ in, unsigned short* __restrict__ out, int R, int C)
{
  __shared__ float tile[32][33];
  const int R0 = blockIdx.y * 32, C0 = blockIdx.x * 32;
  const int t = threadIdx.x;
  const int r = t >> 3, c4 = (t & 7) * 4;
  float4 x = *(const float4*)(in + (size_t)(R0 + r) * C + C0 + c4);
  tile[r][c4+0] = x.x; tile[r][c4+1] = x.y; tile[r][c4+2] = x.z; tile[r][c4+3] = x.w;
  __syncthreads();
  ushort4 o;
  o.x = f2b(tile[c4+0][r]); o.y = f2b(tile[c4+1][r]);
  o.z = f2b(tile[c4+2][r]); o.w = f2b(tile[c4+3][r]);
  *(ushort4*)(out + (size_t)(C0 + r) * R + R0 + c4) = o;
}

// ---------------------------------------------------------------------------
// Transpose V-half of kv into VTg[bh*64 + d][T] (bf16) for PV B-operand.
// ---------------------------------------------------------------------------
__global__ __launch_bounds__(256) void vtrans(
    const unsigned short* __restrict__ kvb, unsigned short* __restrict__ vtg)
{
  __shared__ __align__(16) unsigned short tile[64][72];
  const int t = threadIdx.x;
  const int bh = blockIdx.y;           // b*16+h
  const int b = bh >> 4, h = bh & 15;
  const int t0 = blockIdx.x * 64;
  #pragma unroll
  for (int l = 0; l < 2; ++l){
    int idx = t + l * 256;
    int row = idx >> 3, seg = (idx & 7) * 8;
    u16x8 x = *(const u16x8*)(kvb + ((size_t)(t0 + row) * 4 + b) * 2048 + 1024 + h * 64 + seg);
    *(u16x8*)&tile[row][seg] = x;
  }
  __syncthreads();
  #pragma unroll
  for (int l = 0; l < 2; ++l){
    int idx = t + l * 256;
    int d = idx >> 3, nseg = (idx & 7) * 8;
    u16x8 o;
    #pragma unroll
    for (int j = 0; j < 8; ++j) o[j] = tile[nseg + j][d];
    *(u16x8*)(vtg + ((size_t)bh * 64 + d) * 2048 + t0 + nseg) = o;
  }
}

// LDS layout for async-staged GEMM tiles (m97 pattern, width=16)
#define AS_IDX(row,k) ((((row) >> 3) * 512) + (((k) >> 3) * 64) + (((row) & 7) * 8) + ((k) & 7))

// ---------------------------------------------------------------------------
// Merged projection GEMM: kv (1024 blocks) + q (256) + p (128) in ONE
// dispatch so the small GEMMs don't run at 1 block/CU. All K=1024,
// C = A @ BT^T, 128x128 tiles, bf16 out.
// ---------------------------------------------------------------------------
__global__ __launch_bounds__(256) void gemm_multi(
    const unsigned short* __restrict__ xb,   // (8192,1024)
    const unsigned short* __restrict__ posb, // (2048,1024)
    const unsigned short* __restrict__ WkvT, // (2048,1024)
    const unsigned short* __restrict__ WqT,  // (1024,1024)
    const unsigned short* __restrict__ WpT,  // (1024,1024)
    unsigned short* __restrict__ kvb,        // (8192,2048)
    unsigned short* __restrict__ qbb,        // (4096,1024)
    unsigned short* __restrict__ pbb)        // (2048,1024)
{
  const unsigned short *A, *BT;
  unsigned short* C;
  int N, local;
  int bx = blockIdx.x;
  if (bx < 1024){       A = xb;                       BT = WkvT; C = kvb; N = 2048; local = bx;        }
  else if (bx < 1280){  A = xb + (size_t)4096 * 1024; BT = WqT;  C = qbb; N = 1024; local = bx - 1024; }
  else {                A = posb;                     BT = WpT;  C = pbb; N = 1024; local = bx - 1280; }
  const int nb = N >> 7;
  const int M0 = (local / nb) * 128, N0 = (local % nb) * 128;
  const int K = 1024;

  __shared__ __align__(16) unsigned short As[128 * 64];
  __shared__ __align__(16) unsigned short Bs[128 * 64];
  const int t = threadIdx.x;
  const int w = t >> 6, lane = t & 63, quad = lane >> 4, l16 = lane & 15;
  const int wm = (w >> 1) * 64, wn = (w & 1) * 64;
  const int lr = lane & 7, lcb = lane >> 3;

  f32x4 acc[4][4] = {};

  for (int k0 = 0; k0 < K; k0 += 64){
    __syncthreads();
    #pragma unroll
    for (int i = 0; i < 4; ++i){
      int blk = 4 * w + i;
      gl_lds16(A  + (size_t)(M0 + 8 * blk + lr) * K + k0 + lcb * 8, As + blk * 512);
      gl_lds16(BT + (size_t)(N0 + 8 * blk + lr) * K + k0 + lcb * 8, Bs + blk * 512);
    }
    __syncthreads();
    #pragma unroll
    for (int ks = 0; ks < 2; ++ks){
      short8 af[4], bf[4];
      #pragma unroll
      for (int rt = 0; rt < 4; ++rt)
        af[rt] = *(short8*)&As[AS_IDX(wm + rt * 16 + l16, ks * 32 + quad * 8)];
      #pragma unroll
      for (int ct = 0; ct < 4; ++ct)
        bf[ct] = *(short8*)&Bs[AS_IDX(wn + ct * 16 + l16, ks * 32 + quad * 8)];
      #pragma unroll
      for (int rt = 0; rt < 4; ++rt)
        #pragma unroll
        for (int ct = 0; ct < 4; ++ct)
          acc[rt][ct] = __builtin_amdgcn_mfma_f32_16x16x32_bf16(af[rt], bf[ct], acc[rt][ct], 0, 0, 0);
    }
  }

  #pragma unroll
  for (int rt = 0; rt < 4; ++rt)
    #pragma unroll
    for (int r = 0; r < 4; ++r){
      int row = M0 + wm + rt * 16 + quad * 4 + r;
      #pragma unroll
      for (int ct = 0; ct < 4; ++ct)
        C[(size_t)row * N + N0 + wn + ct * 16 + l16] = f2b(acc[rt][ct][r]);
    }
}

// ---------------------------------------------------------------------------
// Out-projection GEMM, split-K x2: z-half computes K in [z*512, z*512+512),
// writes fp32 partial (no residual) to OutP + z*4096*1024. Grid (8,32,2).
// ---------------------------------------------------------------------------
__global__ __launch_bounds__(256) void gemm_outk(
    const unsigned short* __restrict__ A,    // awvb (4096,1024)
    const unsigned short* __restrict__ BT,   // WoutT (1024,1024)
    float* __restrict__ OutP)                // 2 x (4096,1024) fp32
{
  const int K = 1024, N = 1024;
  const int k0s = blockIdx.z * 512, k0e = k0s + 512;
  float* outF = OutP + (size_t)blockIdx.z * 4096 * 1024;

  __shared__ __align__(16) unsigned short As[128 * 64];
  __shared__ __align__(16) unsigned short Bs[128 * 64];
  const int t = threadIdx.x;
  const int M0 = blockIdx.y * 128, N0 = blockIdx.x * 128;
  const int w = t >> 6, lane = t & 63, quad = lane >> 4, l16 = lane & 15;
  const int wm = (w >> 1) * 64, wn = (w & 1) * 64;
  const int lr = lane & 7, lcb = lane >> 3;

  f32x4 acc[4][4] = {};

  for (int k0 = k0s; k0 < k0e; k0 += 64){
    __syncthreads();
    #pragma unroll
    for (int i = 0; i < 4; ++i){
      int blk = 4 * w + i;
      gl_lds16(A  + (size_t)(M0 + 8 * blk + lr) * K + k0 + lcb * 8, As + blk * 512);
      gl_lds16(BT + (size_t)(N0 + 8 * blk + lr) * K + k0 + lcb * 8, Bs + blk * 512);
    }
    __syncthreads();
    #pragma unroll
    for (int ks = 0; ks < 2; ++ks){
      short8 af[4], bf[4];
      #pragma unroll
      for (int rt = 0; rt < 4; ++rt)
        af[rt] = *(short8*)&As[AS_IDX(wm + rt * 16 + l16, ks * 32 + quad * 8)];
      #pragma unroll
      for (int ct = 0; ct < 4; ++ct)
        bf[ct] = *(short8*)&Bs[AS_IDX(wn + ct * 16 + l16, ks * 32 + quad * 8)];
      #pragma unroll
      for (int rt = 0; rt < 4; ++rt)
        #pragma unroll
        for (int ct = 0; ct < 4; ++ct)
          acc[rt][ct] = __builtin_amdgcn_mfma_f32_16x16x32_bf16(af[rt], bf[ct], acc[rt][ct], 0, 0, 0);
    }
  }

  #pragma unroll
  for (int rt = 0; rt < 4; ++rt)
    #pragma unroll
    for (int r = 0; r < 4; ++r){
      int row = M0 + wm + rt * 16 + quad * 4 + r;
      #pragma unroll
      for (int ct = 0; ct < 4; ++ct)
        outF[(size_t)row * N + N0 + wn + ct * 16 + l16] = acc[rt][ct][r];
    }
}

// ---------------------------------------------------------------------------
// MFMA flash attention, fused Transformer-XL rel-shift, split-j x2.
// Block (i0, bh, jh) handles key chunks jc in [jh*16, jh*16+16); fixed-max
// softmax exp(s-16) makes the two halves exactly combinable via
// (Sum e*V, Sum e) partials. Writes bf16 O-partial + fp32 lsum-partial.
// ---------------------------------------------------------------------------
__global__ __launch_bounds__(256, 3) void attn_mfma(
    const unsigned short* __restrict__ qb,   // (4096,1024) bf16
    const unsigned short* __restrict__ kvb,  // (8192,2048) bf16 [k|v]
    const unsigned short* __restrict__ pbm,  // (2048,1024) bf16
    const unsigned short* __restrict__ vtg,  // (64*64, 2048) bf16 V^T per (b,h)
    const float* __restrict__ ub, const float* __restrict__ vb,
    unsigned short* __restrict__ opart,      // 2 x (4096,1024) bf16 partials
    float* __restrict__ lpart)               // 2 x (4096,16) fp32 partials
{
  __shared__ __align__(16) unsigned short Kc[64 * 64];   // swizzled
  __shared__ __align__(16) unsigned short VT[64 * 64];   // swizzled
  __shared__ __align__(16) unsigned short Pw[128 * 64];  // swizzled
  __shared__ __align__(16) unsigned short Pb[64 * 72];   // padded (scalar writes)
  __shared__ unsigned short Sc[64 * 65];                 // shifted pos scores (bf16)

  const int t = threadIdx.x;
  const int i0 = blockIdx.x * 64;
  const int bh = blockIdx.y;
  const int jh = blockIdx.z;
  const int b = bh >> 4, h = bh & 15;
  const int w = t >> 6, lane = t & 63, quad = lane >> 4, l16 = lane & 15;
  const int colbase = h * 64 + quad * 8;
  const int ctLo = 3 - w;                    // wave-trimmed window range [ctLo, ctLo+4]

  // ---- register A-fragments: qu[ks], qv[cs][ks] (wave rows 16w+l16(+cs)) ----
  short8 qu[2], qv[2][2];
  #pragma unroll
  for (int cs = 0; cs < 2; ++cs){
    int gr = i0 + 16 * w + l16 + cs;         // gr==1024 possible: harmless (masked by n<64)
    #pragma unroll
    for (int ks = 0; ks < 2; ++ks){
      u16x8 q8 = *(const u16x8*)(qb + ((size_t)gr * 4 + b) * 1024 + colbase + ks * 32);
      #pragma unroll
      for (int j = 0; j < 8; ++j){
        float f = b2f(q8[j]);
        qv[cs][ks][j] = (short)f2b(f + vb[colbase + ks * 32 + j]);
        if (cs == 0) qu[ks][j] = (short)f2b(f + ub[colbase + ks * 32 + j]);
      }
    }
  }

  f32x4 oacc[4] = {};                        // [d-tile], rows = quad*4+r
  float lsum[4] = {0.f, 0.f, 0.f, 0.f};

  // staging prefetch registers
  u16x8 pk[2], pv2[2], pp[4];

  auto loadRegs = [&](int jc){
    const int j0 = jc * 64;
    const int D = j0 - i0;
    #pragma unroll
    for (int l = 0; l < 2; ++l){
      int idx = t + l * 256;
      int row = idx >> 3, cb = idx & 7;
      pk[l]  = *(const u16x8*)(kvb + ((size_t)(j0 + row) * 4 + b) * 2048 + h * 64 + cb * 8);
      pv2[l] = *(const u16x8*)(vtg + ((size_t)bh * 64 + row) * 2048 + j0 + cb * 8);
    }
    #pragma unroll
    for (int l = 0; l < 4; ++l){
      int idx = t + l * 256;
      int row = idx >> 3, cb = idx & 7;
      int pr;
      if (D <= 960)          pr = D + 960 + row;
      else if (D == 1024)    pr = (row < 64) ? (1984 + row) : (row - 65);
      else                   pr = D - 1089 + row;
      u16x8 x;
      if (pr >= 0 && pr < T_){
        x = *(const u16x8*)(pbm + (size_t)pr * 1024 + h * 64 + cb * 8);
      } else {
        for (int j = 0; j < 8; ++j) x[j] = 0;
      }
      pp[l] = x;
    }
  };

  auto storeRegs = [&](){
    #pragma unroll
    for (int l = 0; l < 2; ++l){
      int idx = t + l * 256;
      int row = idx >> 3, cb = idx & 7;
      int sw = (cb ^ (row & 7)) * 8;
      *(u16x8*)&Kc[row * 64 + sw] = pk[l];
      *(u16x8*)&VT[row * 64 + sw] = pv2[l];
    }
    #pragma unroll
    for (int l = 0; l < 4; ++l){
      int idx = t + l * 256;
      int row = idx >> 3, cb = idx & 7;
      *(u16x8*)&Pw[row * 64 + ((cb ^ (row & 7)) * 8)] = pp[l];
    }
  };

  const int jcs = jh * 16, jce = jcs + 16;
  loadRegs(jcs);

  #pragma unroll 1
  for (int jc = jcs; jc < jce; ++jc){
    const int j0 = jc * 64;
    const int D = j0 - i0;

    __syncthreads();                         // (1) prev chunk's LDS reads done
    storeRegs();
    if (jc + 1 < jce) loadRegs(jc + 1);      // prefetch next chunk during compute
    __syncthreads();                         // (2) staging visible

    // ---- pos scores: 5 trimmed windows, writer-side shift scatter ----
    #pragma unroll
    for (int ci = 0; ci < 5; ++ci){
      int ct = ctLo + ci;
      int cs = (D <= 960) ? 0 : ((D >= 1088) ? 1 : ((ct >= 4) ? 1 : 0));
      f32x4 racc = {};
      #pragma unroll
      for (int ks = 0; ks < 2; ++ks){
        int rr = ct * 16 + l16;
        short8 bf = *(short8*)&Pw[rr * 64 + (((ks * 4 + quad) ^ (rr & 7)) * 8)];
        racc = __builtin_amdgcn_mfma_f32_16x16x32_bf16(qv[cs][ks], bf, racc, 0, 0, 0);
      }
      int c = ct * 16 + l16;
      #pragma unroll
      for (int r = 0; r < 4; ++r){
        int gm = 16 * w + quad * 4 + r;
        int n = c + gm - 63;
        if ((unsigned)n < 64u) Sc[gm * 65 + n] = f2bt(racc[r]);
      }
    }

    // ---- content scores ----
    f32x4 cacc[4] = {};
    #pragma unroll
    for (int ks = 0; ks < 2; ++ks){
      #pragma unroll
      for (int ct = 0; ct < 4; ++ct){
        int rr = ct * 16 + l16;
        short8 bf = *(short8*)&Kc[rr * 64 + (((ks * 4 + quad) ^ (rr & 7)) * 8)];
        cacc[ct] = __builtin_amdgcn_mfma_f32_16x16x32_bf16(qu[ks], bf, cacc[ct], 0, 0, 0);
      }
    }

    // ---- fixed-max softmax: e = exp(s-16); own-wave LDS rows ----
    #pragma unroll
    for (int ct = 0; ct < 4; ++ct){
      #pragma unroll
      for (int r = 0; r < 4; ++r){
        int gm = 16 * w + quad * 4 + r;
        int n = ct * 16 + l16;
        float s = (cacc[ct][r] + b2f(Sc[gm * 65 + n])) * 0.125f;
        float e = __expf(s - 16.f);
        lsum[r] += e;
        Pb[gm * 72 + n] = f2bt(e);
      }
    }

    // ---- PV: A-frag from own-wave Pb, B-frag from swizzled VT ----
    #pragma unroll
    for (int ks = 0; ks < 2; ++ks){
      short8 af = *(short8*)&Pb[(16 * w + l16) * 72 + ks * 32 + quad * 8];
      #pragma unroll
      for (int dt = 0; dt < 4; ++dt){
        int rr = dt * 16 + l16;
        short8 bf = *(short8*)&VT[rr * 64 + (((ks * 4 + quad) ^ (rr & 7)) * 8)];
        oacc[dt] = __builtin_amdgcn_mfma_f32_16x16x32_bf16(af, bf, oacc[dt], 0, 0, 0);
      }
    }
  }

  // ---- epilogue: reduce row sums, store bf16 O-partial + fp32 l-partial ----
  unsigned short* ob = opart + (size_t)jh * 4096 * 1024;
  float* lb = lpart + (size_t)jh * 4096 * 16;
  #pragma unroll
  for (int r = 0; r < 4; ++r){
    float red = lsum[r];
    #pragma unroll
    for (int mk = 1; mk < 16; mk <<= 1)
      red += __shfl_xor(red, mk, 64);
    int srow = i0 + 16 * w + quad * 4 + r;
    int grow = srow * 4 + b;
    #pragma unroll
    for (int dt = 0; dt < 4; ++dt)
      ob[(size_t)grow * 1024 + h * 64 + dt * 16 + l16] = f2bt(oacc[dt][r]);
    if (l16 == 0) lb[(size_t)grow * 16 + h] = red;
  }
}

// ---------------------------------------------------------------------------
// Combine the two j-half partials: awv = (O0 + O1) / (l0 + l1), bf16 out.
// ---------------------------------------------------------------------------
__global__ __launch_bounds__(256) void attn_combine(
    const unsigned short* __restrict__ opart, const float* __restrict__ lpart,
    unsigned short* __restrict__ awvb)
{
  const int grow = blockIdx.x, t = threadIdx.x;
  const int d4 = t * 4, h = t >> 4;
  float l = lpart[(size_t)grow * 16 + h] + lpart[(size_t)4096 * 16 + grow * 16 + h];
  float inv = 1.f / l;
  ushort4 a = *(const ushort4*)(opart + (size_t)grow * 1024 + d4);
  ushort4 c = *(const ushort4*)(opart + (size_t)4096 * 1024 + grow * 1024 + d4);
  ushort4 o;
  o.x = f2bt((b2f(a.x) + b2f(c.x)) * inv);
  o.y = f2bt((b2f(a.y) + b2f(c.y)) * inv);
  o.z = f2bt((b2f(a.z) + b2f(c.z)) * inv);
  o.w = f2bt((b2f(a.w) + b2f(c.w)) * inv);
  *(ushort4*)(awvb + (size_t)grow * 1024 + d4) = o;
}

// ---------------------------------------------------------------------------
// LayerNorm over last dim: out = LN(input + P0 + P1) * g + b  (fp32 out).
// ---------------------------------------------------------------------------
__global__ __launch_bounds__(256) void ln2_kernel(
    const float* __restrict__ inp, const float* __restrict__ OutP,
    const float* __restrict__ g, const float* __restrict__ bb,
    float* __restrict__ out)
{
  const int row = blockIdx.x, t = threadIdx.x;
  float4 x  = *(const float4*)(inp  + (size_t)row * 1024 + t * 4);
  float4 p0 = *(const float4*)(OutP + (size_t)row * 1024 + t * 4);
  float4 p1 = *(const float4*)(OutP + (size_t)4096 * 1024 + row * 1024 + t * 4);
  x.x += p0.x + p1.x; x.y += p0.y + p1.y; x.z += p0.z + p1.z; x.w += p0.w + p1.w;
  float s  = x.x + x.y + x.z + x.w;
  float s2 = x.x*x.x + x.y*x.y + x.z*x.z + x.w*x.w;
  #pragma unroll
  for (int o = 32; o > 0; o >>= 1){
    s  += __shfl_down(s, o);
    s2 += __shfl_down(s2, o);
  }
  __shared__ float rs[4], rs2[4];
  int w = t >> 6, lane = t & 63;
  if (lane == 0){ rs[w] = s; rs2[w] = s2; }
  __syncthreads();
  s  = rs[0] + rs[1] + rs[2] + rs[3];
  s2 = rs2[0] + rs2[1] + rs2[2] + rs2[3];
  float mu   = s * (1.f/1024.f);
  float var  = s2 * (1.f/1024.f) - mu*mu;
  float rstd = rsqrtf(var + 1e-5f);
  float4 gg = *(const float4*)(g + t*4);
  float4 bv = *(const float4*)(bb + t*4);
  float4 o;
  o.x = (x.x - mu)*rstd*gg.x + bv.x;
  o.y = (x.y - mu)*rstd*gg.y + bv.y;
  o.z = (x.z - mu)*rstd*gg.z + bv.z;
  o.w = (x.w - mu)*rstd*gg.w + bv.w;
  *(float4*)(out + (size_t)row * 1024 + t * 4) = o;
}

extern "C" void kernel_launch(void* const* d_in, const int* in_sizes, int n_in,
                              void* d_out, int out_size, void* d_ws, size_t ws_size,
                              hipStream_t stream) {
  (void)in_sizes; (void)n_in; (void)out_size; (void)ws_size;
  const float* input_ = (const float*)d_in[0];
  const float* pos    = (const float*)d_in[1];
  const float* mem    = (const float*)d_in[2];
  const float* u      = (const float*)d_in[3];
  const float* v      = (const float*)d_in[4];
  const float* Wkv    = (const float*)d_in[5];
  const float* Wq     = (const float*)d_in[6];
  const float* Wp     = (const float*)d_in[7];
  const float* Wout   = (const float*)d_in[8];
  const float* lng    = (const float*)d_in[9];
  const float* lnb    = (const float*)d_in[10];
  float* out = (float*)d_out;

  unsigned short* ws   = (unsigned short*)d_ws;
  unsigned short* xb    = ws;                               // 8192*1024
  unsigned short* posb  = xb    + (size_t)8192*1024;        // 2048*1024
  unsigned short* WkvT  = posb  + (size_t)2048*1024;        // 2048*1024
  unsigned short* WqT   = WkvT  + (size_t)2048*1024;        // 1024*1024
  unsigned short* WpT   = WqT   + (size_t)1024*1024;        // 1024*1024
  unsigned short* WoutT = WpT   + (size_t)1024*1024;        // 1024*1024
  unsigned short* kvb   = WoutT + (size_t)1024*1024;        // 8192*2048
  unsigned short* qbb   = kvb   + (size_t)8192*2048;        // 4096*1024
  unsigned short* pbb   = qbb   + (size_t)4096*1024;        // 2048*1024
  unsigned short* vtg   = pbb   + (size_t)2048*1024;        // 4096*2048
  unsigned short* awvb  = vtg   + (size_t)4096*2048;        // 4096*1024

  // overlays (lifetime-disjoint):
  unsigned short* opart = xb;                 // 2 x 4096*1024 bf16; xb dead after gemm_multi
  float*          lpart = (float*)posb;       // 2 x 4096*16 fp32;  posb dead after gemm_multi
  float*          OutP  = (float*)kvb;        // 2 x 4096*1024 fp32; kvb dead after attn

  // convert inputs to bf16
  cvt_cat<<<8192, 256, 0, stream>>>(mem, input_, 4096*1024, 8192*1024, xb);
  cvt_cat<<<2048, 256, 0, stream>>>(pos, pos, 2048*1024, 2048*1024, posb);
  wtrans<<<dim3(64, 32), 256, 0, stream>>>(Wkv,  WkvT, 1024, 2048);
  wtrans<<<dim3(32, 32), 256, 0, stream>>>(Wq,   WqT,  1024, 1024);
  wtrans<<<dim3(32, 32), 256, 0, stream>>>(Wp,   WpT,  1024, 1024);
  wtrans<<<dim3(32, 32), 256, 0, stream>>>(Wout, WoutT,1024, 1024);

  // merged projections (kv + q + p) in one dispatch
  gemm_multi<<<1408, 256, 0, stream>>>(xb, posb, WkvT, WqT, WpT, kvb, qbb, pbb);

  // V transpose for PV B-operand
  vtrans<<<dim3(32, 64), 256, 0, stream>>>(kvb, vtg);

  // fused rel-shift MFMA flash attention, split-j x2
  attn_mfma<<<dim3(16, 64, 2), 256, 0, stream>>>(qbb, kvb, pbb, vtg, u, v, opart, lpart);
  attn_combine<<<4096, 256, 0, stream>>>(opart, lpart, awvb);

  // out-projection, split-K x2 (fp32 partials), then fused residual+LN
  gemm_outk<<<dim3(8, 32, 2), 256, 0, stream>>>(awvb, WoutT, OutP);
  ln2_kernel<<<4096, 256, 0, stream>>>(input_, OutP, lng, lnb, out);
}